// Round 5
// baseline (307.325 us; speedup 1.0000x reference)
//
#include <hip/hip_runtime.h>
#include <hip/hip_bf16.h>

typedef __bf16 bf16;
typedef __attribute__((ext_vector_type(8))) __bf16 bf16x8;
typedef __attribute__((ext_vector_type(4))) __bf16 bf16x4;
typedef __attribute__((ext_vector_type(2))) __bf16 bf16x2;
typedef __attribute__((ext_vector_type(4))) float f32x4;

#define NTOK 98
#define NP   112
#define DIM  128
#define NH   4
#define HD   32
#define LOG2E 1.4426950408889634f
// SCALE_Q * log2(e): scores arrive pre-scaled for exp2
#define SCALE_Q2 (0.17677669529663687f * 1.4426950408889634f)
#define SCALE_Q 0.17677669529663687f

#define SXP 136
#define SKP 40
#define SVP 136
#define SPP 136
#define SQP 40
#define STGP 40          // staging pitch (elems)
#define HREG 2560        // per-head staging region (elems) = 2 x 32 x STGP

// ---- fast-path ws layout (bytes) ----
#define WS_WTQ  0ULL                    // bf16 [384][128]            98304
#define WS_PT   98304ULL                // bf16 [128][128]            32768
#define WS_BM   131072ULL               // f32  [64][4][112][112]  12845056
#define WS_NEED 12976128ULL

#define PREP_SCALAR (384*128 + 128*128)   // 65536
#define PREP_BM_V4  (64*4*112*28)         // 802816 (4 k per item)

// ===================== prep kernel (merged) =====================
// WTq[n][k] = qkv_w[k][n]  (natural)
// PT2[n][j] = proj_w[nat(j)][n], nat(j) de-interleaves the O store layout
// bmt[w][h][q 112][k 112] = (table+mask)*log2e; k>=98 -> -1e30; q>=98 -> 0.
// bm part vectorized: one item = 4 consecutive k (f32x4 write, merged loads).
__global__ __launch_bounds__(256) void prep3_kernel(
    const float* __restrict__ qkv_w, const float* __restrict__ proj_w,
    const float* __restrict__ table, const int* __restrict__ rel,
    const float* __restrict__ mask,
    bf16* __restrict__ WTq, bf16* __restrict__ PT2, float* __restrict__ bmt)
{
  int i = blockIdx.x * 256 + threadIdx.x;
  if (i < 384*128) {
    int n = i >> 7, k = i & 127;
    WTq[i] = (bf16)qkv_w[k*384 + n];
  } else if (i < PREP_SCALAR) {
    int j = i - 384*128; int n = j >> 7, kp = j & 127;
    int blk = kp >> 5, jl = kp & 31;
    int dl = (jl >> 1) + 16*(jl & 1);
    PT2[j] = (bf16)proj_w[(blk*32 + dl)*128 + n];
  } else {
    int g = i - PREP_SCALAR;
    if (g >= PREP_BM_V4) return;
    int k4 = (g % 28) * 4;
    int rest = g / 28;
    int q = rest % 112;
    int rest2 = rest / 112;
    int h = rest2 & 3;
    int w = rest2 >> 2;
    f32x4 v;
    if (q >= NTOK) {
      v[0] = 0.f; v[1] = 0.f; v[2] = 0.f; v[3] = 0.f;
    } else {
#pragma unroll
      for (int j = 0; j < 4; ++j) {
        int k = k4 + j;
        if (k >= NTOK) v[j] = -1.0e30f;
        else v[j] = (table[rel[q*98 + k]*4 + h] + mask[w*9604 + q*98 + k]) * LOG2E;
      }
    }
    *(f32x4*)(bmt + ((size_t)(w*4 + h))*(NP*NP) + q*NP + k4) = v;
  }
}

// ===================== fused qkv + attention + proj =====================
// One block per window. 4 waves, wave = head. Q/K/V stay on-chip.
// S^T orientation: s = mfma(K,Q) -> lane owns scores of q-row (mt*16+l16).
// exp2-native softmax (Q and bmt pre-scaled by log2e), no max-subtract,
// normalization deferred to the O-write (inv transposed via lane shuffles).
// bm tiles register-double-buffered across mt (L3 latency hidden); setprio
// around MFMA clusters.
__global__ __launch_bounds__(256, 3) void fused_kernel(
    const float* __restrict__ x, const float* __restrict__ qkv_b,
    const float* __restrict__ proj_b,
    const bf16* __restrict__ WTq, const bf16* __restrict__ PT2,
    const float* __restrict__ bmt, float* __restrict__ out)
{
  __shared__ alignas(16) bf16 sA[NP*SXP];      // x staged -> later O
  __shared__ alignas(16) bf16 sB[4*HREG];      // per-head staging -> later P

  const int b = blockIdx.x, w = b & 63;
  const int tid = threadIdx.x;
  const int wave = tid >> 6, lane = tid & 63;
  const int quad = lane >> 4, l16 = lane & 15;
  const int h = wave;
  const f32x4 fzero = {0.f, 0.f, 0.f, 0.f};

  // ---- phase 0: stage x -> sA (bf16, rows 98..111 zero) ----
  {
    const float* xb = x + (size_t)b * (NTOK*DIM);
    for (int i = tid; i < NTOK*32; i += 256) {
      int row = i >> 5, c4 = (i & 31) << 2;
      const float4 v = *(const float4*)(xb + row*DIM + c4);
      bf16x4 pk; pk[0]=(bf16)v.x; pk[1]=(bf16)v.y; pk[2]=(bf16)v.z; pk[3]=(bf16)v.w;
      *(bf16x4*)&sA[row*SXP + c4] = pk;
    }
    for (int i = tid; i < 14*32; i += 256) {
      int row = NTOK + (i >> 5), c4 = (i & 31) << 2;
      uint2 z; z.x = 0; z.y = 0;
      *(uint2*)&sA[row*SXP + c4] = z;
    }
  }
  __syncthreads();

  bf16* stg = sB + h*HREG;
  bf16x8 bk[7], aq[7], bv[2][4];

  // ---- phase 1ab: K + Q fragments (merged, d-interleaved packed stores) ----
  {
    const int baseK = DIM + h*HD, baseQ = h*HD;
    bf16x8 wK0[4], wK1[4], wQ0[4], wQ1[4];
#pragma unroll
    for (int ks = 0; ks < 4; ++ks) {
      wK0[ks] = *(const bf16x8*)(WTq + (baseK + l16)*DIM + ks*32 + quad*8);
      wK1[ks] = *(const bf16x8*)(WTq + (baseK + 16 + l16)*DIM + ks*32 + quad*8);
      wQ0[ks] = *(const bf16x8*)(WTq + (baseQ + l16)*DIM + ks*32 + quad*8);
      wQ1[ks] = *(const bf16x8*)(WTq + (baseQ + 16 + l16)*DIM + ks*32 + quad*8);
    }
    const float cK0 = qkv_b[baseK + l16], cK1 = qkv_b[baseK + 16 + l16];
    const float cQ0 = qkv_b[baseQ + l16], cQ1 = qkv_b[baseQ + 16 + l16];
#pragma unroll
    for (int mt = 0; mt < 7; ++mt) {
      f32x4 k0 = fzero, k1 = fzero, q0 = fzero, q1 = fzero;
      __builtin_amdgcn_s_setprio(1);
#pragma unroll
      for (int ks = 0; ks < 4; ++ks) {
        const bf16x8 a = *(const bf16x8*)&sA[(mt*16 + l16)*SXP + ks*32 + quad*8];
        k0 = __builtin_amdgcn_mfma_f32_16x16x32_bf16(a, wK0[ks], k0, 0, 0, 0);
        k1 = __builtin_amdgcn_mfma_f32_16x16x32_bf16(a, wK1[ks], k1, 0, 0, 0);
        q0 = __builtin_amdgcn_mfma_f32_16x16x32_bf16(a, wQ0[ks], q0, 0, 0, 0);
        q1 = __builtin_amdgcn_mfma_f32_16x16x32_bf16(a, wQ1[ks], q1, 0, 0, 0);
      }
      __builtin_amdgcn_s_setprio(0);
#pragma unroll
      for (int r = 0; r < 4; ++r) {
        bf16x2 pk; pk[0] = (bf16)(k0[r] + cK0); pk[1] = (bf16)(k1[r] + cK1);
        *(bf16x2*)&stg[(quad*4 + r)*STGP + l16*2] = pk;
        bf16x2 pq; pq[0] = (bf16)((q0[r] + cQ0) * SCALE_Q2);
        pq[1] = (bf16)((q1[r] + cQ1) * SCALE_Q2);
        *(bf16x2*)&stg[(16 + quad*4 + r)*STGP + l16*2] = pq;
      }
      bk[mt] = *(const bf16x8*)&stg[l16*STGP + quad*8];
      aq[mt] = *(const bf16x8*)&stg[(16 + l16)*STGP + quad*8];
    }
  }

  // ---- phase 1c: V^T fragments (natural token order) ----
  {
    const int baseV = 2*DIM + h*HD;
    bf16x8 wV0[4], wV1[4];
#pragma unroll
    for (int ks = 0; ks < 4; ++ks) {
      wV0[ks] = *(const bf16x8*)(WTq + (baseV + l16)*DIM + ks*32 + quad*8);
      wV1[ks] = *(const bf16x8*)(WTq + (baseV + 16 + l16)*DIM + ks*32 + quad*8);
    }
    const float cV0 = qkv_b[baseV + l16], cV1 = qkv_b[baseV + 16 + l16];
#pragma unroll
    for (int ck = 0; ck < 4; ++ck) {
      bf16* vb = stg + (ck & 1)*1280;
#pragma unroll
      for (int hf = 0; hf < 2; ++hf) {
        const int mt = ck*2 + hf;
        if (mt < 7) {
          f32x4 a0 = fzero, a1 = fzero;
          __builtin_amdgcn_s_setprio(1);
#pragma unroll
          for (int ks = 0; ks < 4; ++ks) {
            const bf16x8 a = *(const bf16x8*)&sA[(mt*16 + l16)*SXP + ks*32 + quad*8];
            a0 = __builtin_amdgcn_mfma_f32_16x16x32_bf16(a, wV0[ks], a0, 0, 0, 0);
            a1 = __builtin_amdgcn_mfma_f32_16x16x32_bf16(a, wV1[ks], a1, 0, 0, 0);
          }
          __builtin_amdgcn_s_setprio(0);
          bf16x4 p0, p1;
#pragma unroll
          for (int r = 0; r < 4; ++r) { p0[r] = (bf16)(a0[r] + cV0); p1[r] = (bf16)(a1[r] + cV1); }
          *(bf16x4*)&vb[l16*STGP + hf*16 + quad*4] = p0;
          *(bf16x4*)&vb[(16 + l16)*STGP + hf*16 + quad*4] = p1;
        } else {
          uint2 z; z.x = 0; z.y = 0;
          *(uint2*)&vb[l16*STGP + hf*16 + quad*4] = z;
          *(uint2*)&vb[(16 + l16)*STGP + hf*16 + quad*4] = z;
        }
      }
      bv[0][ck] = *(const bf16x8*)&vb[l16*STGP + quad*8];
      bv[1][ck] = *(const bf16x8*)&vb[(16 + l16)*STGP + quad*8];
    }
  }
  __syncthreads();   // all waves done reading x from sA; sA becomes O

  // ---- phase 2: attention, S^T orientation ----
  bf16* sP = stg;    // 16 x SPP, overlays dead staging
  {   // zero P pad cols 112..127 once
    int row = lane >> 2, c0 = 112 + ((lane & 3) << 2);
    uint2 z; z.x = 0; z.y = 0;
    *(uint2*)&sP[row*SPP + c0] = z;
  }
  const float* bmh = bmt + ((size_t)(w*4 + h))*(NP*NP);

  // register-double-buffered bias+mask tiles (hide L3 latency across mt)
  f32x4 bmc[7];
#pragma unroll
  for (int nt = 0; nt < 7; ++nt)
    bmc[nt] = *(const f32x4*)(bmh + l16*NP + nt*16 + quad*4);

#pragma unroll
  for (int mt = 0; mt < 7; ++mt) {
    // S^T[k][q]: lane owns q-row (mt*16+l16), k = nt*16 + quad*4 + r
    f32x4 s[7];
    __builtin_amdgcn_s_setprio(1);
#pragma unroll
    for (int nt = 0; nt < 7; ++nt)
      s[nt] = __builtin_amdgcn_mfma_f32_16x16x32_bf16(bk[nt], aq[mt], fzero, 0, 0, 0);
    __builtin_amdgcn_s_setprio(0);
    // prefetch next mt's bm tiles while this mt computes
    f32x4 bmn[7];
    if (mt < 6) {
      const float* bqn = bmh + ((mt+1)*16 + l16)*NP;
#pragma unroll
      for (int nt = 0; nt < 7; ++nt)
        bmn[nt] = *(const f32x4*)(bqn + nt*16 + quad*4);
    }
    // add pre-scaled bias+mask, exp2 (native v_exp_f32)
#pragma unroll
    for (int nt = 0; nt < 7; ++nt) {
      s[nt] = s[nt] + bmc[nt];
#pragma unroll
      for (int r = 0; r < 4; ++r)
        s[nt][r] = __builtin_amdgcn_exp2f(s[nt][r]);
    }
    // P-hat store (unnormalized), packed b64, natural k order
#pragma unroll
    for (int nt = 0; nt < 7; ++nt) {
      bf16x4 pk;
#pragma unroll
      for (int r = 0; r < 4; ++r) pk[r] = (bf16)s[nt][r];
      *(bf16x4*)&sP[l16*SPP + nt*16 + quad*4] = pk;
    }
    // O-tile = P-hat V issued first; the sum/shuffle chain runs concurrently
    f32x4 o0 = fzero, o1 = fzero;
    __builtin_amdgcn_s_setprio(1);
#pragma unroll
    for (int ks = 0; ks < 4; ++ks) {
      const bf16x8 ap = *(const bf16x8*)&sP[l16*SPP + ks*32 + quad*8];
      o0 = __builtin_amdgcn_mfma_f32_16x16x32_bf16(ap, bv[0][ks], o0, 0, 0, 0);
      o1 = __builtin_amdgcn_mfma_f32_16x16x32_bf16(ap, bv[1][ks], o1, 0, 0, 0);
    }
    __builtin_amdgcn_s_setprio(0);
    // row sum for q = mt*16 + l16: in-register tree + 2 shuffles
    float rs[7];
#pragma unroll
    for (int nt = 0; nt < 7; ++nt)
      rs[nt] = (s[nt][0] + s[nt][1]) + (s[nt][2] + s[nt][3]);
    float sum = ((rs[0] + rs[1]) + (rs[2] + rs[3])) + ((rs[4] + rs[5]) + rs[6]);
    sum += __shfl_xor(sum, 16);
    sum += __shfl_xor(sum, 32);
    const float inv = __builtin_amdgcn_rcpf(sum);   // inv for q-row = mt*16 + l16
    // PV output rows are q = mt*16 + quad*4 + r -> transpose inv via shuffles
    float invr[4];
#pragma unroll
    for (int r = 0; r < 4; ++r)
      invr[r] = __shfl(inv, quad*4 + r, 64);
#pragma unroll
    for (int r = 0; r < 4; ++r) {
      bf16x2 ow; ow[0] = (bf16)(o0[r]*invr[r]); ow[1] = (bf16)(o1[r]*invr[r]);
      *(bf16x2*)&sA[(mt*16 + quad*4 + r)*SXP + h*HD + l16*2] = ow;
    }
    if (mt < 6) {
#pragma unroll
      for (int nt = 0; nt < 7; ++nt) bmc[nt] = bmn[nt];
    }
  }
  __syncthreads();

  // ---- phase 3: proj GEMM from sA(O, interleaved) with PT2; waves do col-tiles {wave, wave+4}
  float* outb = out + (size_t)b * (NTOK*DIM);
#pragma unroll
  for (int nn = 0; nn < 2; ++nn) {
    const int nt2 = wave + nn*4;
    bf16x8 pf[4];
#pragma unroll
    for (int ks = 0; ks < 4; ++ks)
      pf[ks] = *(const bf16x8*)(PT2 + (nt2*16 + l16)*DIM + ks*32 + quad*8);
    const float pb = proj_b[nt2*16 + l16];
#pragma unroll
    for (int mt = 0; mt < 7; ++mt) {
      f32x4 acc = fzero;
      __builtin_amdgcn_s_setprio(1);
#pragma unroll
      for (int ks = 0; ks < 4; ++ks) {
        const bf16x8 a = *(const bf16x8*)&sA[(mt*16 + l16)*SXP + ks*32 + quad*8];
        acc = __builtin_amdgcn_mfma_f32_16x16x32_bf16(a, pf[ks], acc, 0, 0, 0);
      }
      __builtin_amdgcn_s_setprio(0);
#pragma unroll
      for (int r = 0; r < 4; ++r) {
        const int row = mt*16 + quad*4 + r;
        if (row < NTOK)
          outb[row*DIM + nt2*16 + l16] = acc[r] + pb;
      }
    }
  }
}

// ===================== fallback path (used if ws too small) =====================

__global__ __launch_bounds__(256) void prep_kernel(
    const float* __restrict__ qkv_w, const float* __restrict__ proj_w,
    const float* __restrict__ table, const int* __restrict__ rel_index,
    bf16* __restrict__ WTq, bf16* __restrict__ PT, float* __restrict__ biasf)
{
  int i = blockIdx.x * 256 + threadIdx.x;
  if (i < 384*128) {
    int n = i >> 7, k = i & 127;
    WTq[i] = (bf16)qkv_w[k*384 + n];
  } else if (i < 384*128 + 128*128) {
    int j = i - 384*128; int n = j >> 7, k = j & 127;
    PT[j] = (bf16)proj_w[k*128 + n];
  } else if (i < 384*128 + 128*128 + 98*98) {
    int j = i - (384*128 + 128*128);
    int idx = rel_index[j];
#pragma unroll
    for (int h = 0; h < 4; ++h) biasf[h*9604 + j] = table[idx*4 + h];
  }
}

__global__ __launch_bounds__(512, 2) void win_attn_kernel(
    const float* __restrict__ x, const float* __restrict__ mask,
    const float* __restrict__ qkv_b, const float* __restrict__ proj_b,
    const bf16* __restrict__ WTq, const bf16* __restrict__ PT,
    const float* __restrict__ biasf, float* __restrict__ out)
{
  __shared__ bf16 sX[NP*SXP];
  __shared__ bf16 sK[NH*NP*SKP];
  __shared__ bf16 sVT[NH*HD*SVP];
  __shared__ bf16 sQs[8*16*SQP];
  __shared__ bf16 sPs[8*16*SPP];

  const int b = blockIdx.x;
  const int w = b & 63;
  const int tid = threadIdx.x;
  const int wave = tid >> 6, lane = tid & 63;
  const int quad = lane >> 4, l16 = lane & 15;
  const f32x4 fzero = {0.f, 0.f, 0.f, 0.f};

  {
    const float* xb = x + (size_t)b * (NTOK*DIM);
    for (int i = tid; i < NTOK*32; i += 512) {
      int row = i >> 5, c4 = (i & 31) << 2;
      const float4 v = *(const float4*)(xb + row*DIM + c4);
      bf16x4 pk; pk[0]=(bf16)v.x; pk[1]=(bf16)v.y; pk[2]=(bf16)v.z; pk[3]=(bf16)v.w;
      *(bf16x4*)&sX[row*SXP + c4] = pk;
    }
    for (int i = tid; i < 14*32; i += 512) {
      int row = NTOK + (i >> 5), c4 = (i & 31) << 2;
      uint2 z; z.x = 0; z.y = 0;
      *(uint2*)&sX[row*SXP + c4] = z;
    }
    {
      int h = tid >> 7, rem = tid & 127, d = rem >> 2, c0 = 112 + ((rem & 3) << 2);
      uint2 z; z.x = 0; z.y = 0;
      *(uint2*)&sVT[(h*HD + d)*SVP + c0] = z;
    }
  }
  __syncthreads();

#pragma unroll
  for (int j = 0; j < 2; ++j) {
    const int job = wave*2 + j;
    const int h = job >> 2, part = job & 3;
    const bool isK = part < 2;
    const int ncol = (isK ? DIM + h*HD + part*16 : 2*DIM + h*HD + (part-2)*16) + l16;
    bf16x8 bfr[4];
#pragma unroll
    for (int ks = 0; ks < 4; ++ks)
      bfr[ks] = *(const bf16x8*)(WTq + ncol*DIM + ks*32 + quad*8);
    const float cb = qkv_b[ncol];
#pragma unroll
    for (int mt = 0; mt < 7; ++mt) {
      f32x4 acc = fzero;
#pragma unroll
      for (int ks = 0; ks < 4; ++ks) {
        const bf16x8 a = *(const bf16x8*)&sX[(mt*16 + l16)*SXP + ks*32 + quad*8];
        acc = __builtin_amdgcn_mfma_f32_16x16x32_bf16(a, bfr[ks], acc, 0, 0, 0);
      }
      const int tb = mt*16 + quad*4;
      if (isK) {
        const int d = part*16 + l16;
#pragma unroll
        for (int r = 0; r < 4; ++r)
          sK[(h*NP + tb + r)*SKP + d] = (bf16)(acc[r] + cb);
      } else {
        const int d = (part-2)*16 + l16;
        bf16x4 pk;
#pragma unroll
        for (int r = 0; r < 4; ++r) pk[r] = (bf16)(acc[r] + cb);
        *(bf16x4*)&sVT[(h*HD + d)*SVP + tb] = pk;
      }
    }
  }
  __syncthreads();

  {
    const int h = wave >> 1, sub = wave & 1;
    bf16x8 qb[2][4];
#pragma unroll
    for (int nt2 = 0; nt2 < 2; ++nt2)
#pragma unroll
      for (int ks = 0; ks < 4; ++ks)
        qb[nt2][ks] = *(const bf16x8*)(WTq + (h*HD + nt2*16 + l16)*DIM + ks*32 + quad*8);
    const float qbias0 = qkv_b[h*HD + l16];
    const float qbias1 = qkv_b[h*HD + 16 + l16];
    bf16* sQ = sQs + wave*16*SQP;
    bf16* sP = sPs + wave*16*SPP;
    {
      int row = lane >> 2, c0 = 112 + ((lane & 3) << 2);
      uint2 z; z.x = 0; z.y = 0;
      *(uint2*)&sP[row*SPP + c0] = z;
    }
    const float* bias_h = biasf + h*9604;
    const float* mask_w = mask + w*9604;

    f32x4 oacc0 = fzero, oacc1 = fzero;
#pragma unroll 1
    for (int it = 0; it < 4; ++it) {
      const int mt = sub + it*2;
      const bool valid = mt < 7;
      if (valid) {
        f32x4 qa0 = fzero, qa1 = fzero;
#pragma unroll
        for (int ks = 0; ks < 4; ++ks) {
          const bf16x8 a = *(const bf16x8*)&sX[(mt*16 + l16)*SXP + ks*32 + quad*8];
          qa0 = __builtin_amdgcn_mfma_f32_16x16x32_bf16(a, qb[0][ks], qa0, 0, 0, 0);
          qa1 = __builtin_amdgcn_mfma_f32_16x16x32_bf16(a, qb[1][ks], qa1, 0, 0, 0);
        }
#pragma unroll
        for (int r = 0; r < 4; ++r) {
          sQ[(quad*4 + r)*SQP + l16]      = (bf16)((qa0[r] + qbias0) * SCALE_Q);
          sQ[(quad*4 + r)*SQP + 16 + l16] = (bf16)((qa1[r] + qbias1) * SCALE_Q);
        }
        const bf16x8 aq = *(const bf16x8*)&sQ[l16*SQP + quad*8];
        f32x4 s[7];
#pragma unroll
        for (int nt = 0; nt < 7; ++nt) {
          const bf16x8 bk2 = *(const bf16x8*)&sK[(h*NP + nt*16 + l16)*SKP + quad*8];
          s[nt] = __builtin_amdgcn_mfma_f32_16x16x32_bf16(aq, bk2, fzero, 0, 0, 0);
        }
#pragma unroll
        for (int r = 0; r < 4; ++r) {
          const int row = mt*16 + quad*4 + r;
          const bool rowok = row < NTOK;
          float mx = -3.0e38f;
#pragma unroll
          for (int nt = 0; nt < 7; ++nt) {
            const int col = nt*16 + l16;
            float sv;
            if (rowok && col < NTOK)
              sv = s[nt][r] + bias_h[row*NTOK + col] + mask_w[row*NTOK + col];
            else
              sv = -1.0e30f;
            s[nt][r] = sv;
            mx = fmaxf(mx, sv);
          }
#pragma unroll
          for (int off = 1; off < 16; off <<= 1)
            mx = fmaxf(mx, __shfl_xor(mx, off, 64));
          float sum = 0.f;
#pragma unroll
          for (int nt = 0; nt < 7; ++nt) {
            const float p = __expf(s[nt][r] - mx);
            s[nt][r] = p;
            sum += p;
          }
#pragma unroll
          for (int off = 1; off < 16; off <<= 1)
            sum += __shfl_xor(sum, off, 64);
          const float inv = __builtin_amdgcn_rcpf(sum);
#pragma unroll
          for (int nt = 0; nt < 7; ++nt)
            sP[(quad*4 + r)*SPP + nt*16 + l16] = (bf16)(s[nt][r] * inv);
        }
        oacc0 = fzero; oacc1 = fzero;
#pragma unroll
        for (int ks = 0; ks < 4; ++ks) {
          const bf16x8 ap = *(const bf16x8*)&sP[l16*SPP + ks*32 + quad*8];
          const bf16x8 bv0 = *(const bf16x8*)&sVT[(h*HD + l16)*SVP + ks*32 + quad*8];
          const bf16x8 bv1 = *(const bf16x8*)&sVT[(h*HD + 16 + l16)*SVP + ks*32 + quad*8];
          oacc0 = __builtin_amdgcn_mfma_f32_16x16x32_bf16(ap, bv0, oacc0, 0, 0, 0);
          oacc1 = __builtin_amdgcn_mfma_f32_16x16x32_bf16(ap, bv1, oacc1, 0, 0, 0);
        }
      }
      __syncthreads();
      if (valid) {
#pragma unroll
        for (int r = 0; r < 4; ++r) {
          sX[(mt*16 + quad*4 + r)*SXP + h*HD + l16]      = (bf16)(oacc0[r]);
          sX[(mt*16 + quad*4 + r)*SXP + h*HD + 16 + l16] = (bf16)(oacc1[r]);
        }
      }
    }
  }
  __syncthreads();

  {
    const int nt = wave;
    bf16x8 pbf[4];
#pragma unroll
    for (int ks = 0; ks < 4; ++ks)
      pbf[ks] = *(const bf16x8*)(PT + (nt*16 + l16)*DIM + ks*32 + quad*8);
    const float pb = proj_b[nt*16 + l16];
    float* outb = out + (size_t)b * (NTOK*DIM);
#pragma unroll
    for (int mt = 0; mt < 7; ++mt) {
      f32x4 acc = fzero;
#pragma unroll
      for (int ks = 0; ks < 4; ++ks) {
        const bf16x8 a = *(const bf16x8*)&sX[(mt*16 + l16)*SXP + ks*32 + quad*8];
        acc = __builtin_amdgcn_mfma_f32_16x16x32_bf16(a, pbf[ks], acc, 0, 0, 0);
      }
#pragma unroll
      for (int r = 0; r < 4; ++r) {
        const int row = mt*16 + quad*4 + r;
        if (row < NTOK)
          outb[row*DIM + nt*16 + l16] = acc[r] + pb;
      }
    }
  }
}

extern "C" void kernel_launch(void* const* d_in, const int* in_sizes, int n_in,
                              void* d_out, int out_size, void* d_ws, size_t ws_size,
                              hipStream_t stream)
{
  const float* x      = (const float*)d_in[0];
  const float* mask   = (const float*)d_in[1];
  const float* qkv_w  = (const float*)d_in[2];
  const float* qkv_b  = (const float*)d_in[3];
  const float* table  = (const float*)d_in[4];
  const int*   rel    = (const int*)d_in[5];
  const float* proj_w = (const float*)d_in[6];
  const float* proj_b = (const float*)d_in[7];
  float* out = (float*)d_out;
  char* ws = (char*)d_ws;

  if (ws_size >= WS_NEED) {
    bf16*  WTq = (bf16*)(ws + WS_WTQ);
    bf16*  PT2 = (bf16*)(ws + WS_PT);
    float* bmt = (float*)(ws + WS_BM);

    const int prep_total = PREP_SCALAR + PREP_BM_V4;   // 868352
    prep3_kernel<<<(prep_total + 255)/256, 256, 0, stream>>>(
        qkv_w, proj_w, table, rel, mask, WTq, PT2, bmt);
    fused_kernel<<<2048, 256, 0, stream>>>(x, qkv_b, proj_b, WTq, PT2, bmt, out);
  } else {
    bf16*  WTq   = (bf16*)(ws + WS_WTQ);
    bf16*  PT    = (bf16*)(ws + WS_PT);
    float* biasf = (float*)(ws + WS_BM);
    const int prep_total = 384*128 + 128*128 + 98*98;
    prep_kernel<<<(prep_total + 255)/256, 256, 0, stream>>>(qkv_w, proj_w, table, rel, WTq, PT, biasf);
    win_attn_kernel<<<2048, 512, 0, stream>>>(x, mask, qkv_b, proj_b, WTq, PT, biasf, out);
  }
}

// Round 6
// 280.178 us; speedup vs baseline: 1.0969x; 1.0969x over previous
//
#include <hip/hip_runtime.h>
#include <hip/hip_bf16.h>

typedef __bf16 bf16;
typedef __attribute__((ext_vector_type(8))) __bf16 bf16x8;
typedef __attribute__((ext_vector_type(4))) __bf16 bf16x4;
typedef __attribute__((ext_vector_type(2))) __bf16 bf16x2;
typedef __attribute__((ext_vector_type(4))) float f32x4;

#define NTOK 98
#define NP   112
#define DIM  128
#define NH   4
#define HD   32
#define LOG2E 1.4426950408889634f
// SCALE_Q * log2(e): scores arrive pre-scaled for exp2
#define SCALE_Q2 (0.17677669529663687f * 1.4426950408889634f)
#define SCALE_Q 0.17677669529663687f

#define SXP 136
#define SKP 40
#define SVP 136
#define SPP 136
#define SQP 40
#define STGP 40          // staging pitch (elems)
#define HREG 2560        // per-head staging region (elems) = 2 x 32 x STGP

// ---- fast-path ws layout (bytes) ----
#define WS_WTQ  0ULL                    // bf16 [384][128]            98304
#define WS_PT   98304ULL                // bf16 [128][128]            32768
#define WS_BM   131072ULL               // f32  [64][4][112][112]  12845056
#define WS_NEED 12976128ULL

#define PREP_SCALAR (384*128 + 128*128)   // 65536
#define PREP_BM_V4  (64*4*112*28)         // 802816 (4 k per item)

// ===================== prep kernel (merged) =====================
// WTq[n][k] = qkv_w[k][n]  (natural)
// PT2[n][j] = proj_w[nat(j)][n], nat(j) de-interleaves the O store layout
// bmt[w][h][q 112][k 112] = (table+mask)*log2e; k>=98 -> -1e30; q>=98 -> 0.
// bm part vectorized: one item = 4 consecutive k (f32x4 write, merged loads).
__global__ __launch_bounds__(256) void prep3_kernel(
    const float* __restrict__ qkv_w, const float* __restrict__ proj_w,
    const float* __restrict__ table, const int* __restrict__ rel,
    const float* __restrict__ mask,
    bf16* __restrict__ WTq, bf16* __restrict__ PT2, float* __restrict__ bmt)
{
  int i = blockIdx.x * 256 + threadIdx.x;
  if (i < 384*128) {
    int n = i >> 7, k = i & 127;
    WTq[i] = (bf16)qkv_w[k*384 + n];
  } else if (i < PREP_SCALAR) {
    int j = i - 384*128; int n = j >> 7, kp = j & 127;
    int blk = kp >> 5, jl = kp & 31;
    int dl = (jl >> 1) + 16*(jl & 1);
    PT2[j] = (bf16)proj_w[(blk*32 + dl)*128 + n];
  } else {
    int g = i - PREP_SCALAR;
    if (g >= PREP_BM_V4) return;
    int k4 = (g % 28) * 4;
    int rest = g / 28;
    int q = rest % 112;
    int rest2 = rest / 112;
    int h = rest2 & 3;
    int w = rest2 >> 2;
    f32x4 v;
    if (q >= NTOK) {
      v[0] = 0.f; v[1] = 0.f; v[2] = 0.f; v[3] = 0.f;
    } else {
#pragma unroll
      for (int j = 0; j < 4; ++j) {
        int k = k4 + j;
        if (k >= NTOK) v[j] = -1.0e30f;
        else v[j] = (table[rel[q*98 + k]*4 + h] + mask[w*9604 + q*98 + k]) * LOG2E;
      }
    }
    *(f32x4*)(bmt + ((size_t)(w*4 + h))*(NP*NP) + q*NP + k4) = v;
  }
}

// ===================== fused qkv + attention + proj =====================
// One block per window. 4 waves, wave = head. Q/K/V stay on-chip.
// S^T orientation: s = mfma(K,Q) -> lane owns scores of q-row (mt*16+l16).
// exp2-native softmax (Q and bmt pre-scaled by log2e), no max-subtract,
// normalization deferred to the O-write (inv transposed via lane shuffles).
// NOTE r5 post-mortem: bm register double-buffer spilled (>168 VGPR cap at
// 3 waves/SIMD) -> scratch traffic doubled HBM bytes. Keep bm loads direct.
__global__ __launch_bounds__(256, 3) void fused_kernel(
    const float* __restrict__ x, const float* __restrict__ qkv_b,
    const float* __restrict__ proj_b,
    const bf16* __restrict__ WTq, const bf16* __restrict__ PT2,
    const float* __restrict__ bmt, float* __restrict__ out)
{
  __shared__ alignas(16) bf16 sA[NP*SXP];      // x staged -> later O
  __shared__ alignas(16) bf16 sB[4*HREG];      // per-head staging -> later P

  const int b = blockIdx.x, w = b & 63;
  const int tid = threadIdx.x;
  const int wave = tid >> 6, lane = tid & 63;
  const int quad = lane >> 4, l16 = lane & 15;
  const int h = wave;
  const f32x4 fzero = {0.f, 0.f, 0.f, 0.f};

  // ---- phase 0: stage x -> sA (bf16, rows 98..111 zero) ----
  {
    const float* xb = x + (size_t)b * (NTOK*DIM);
    for (int i = tid; i < NTOK*32; i += 256) {
      int row = i >> 5, c4 = (i & 31) << 2;
      const float4 v = *(const float4*)(xb + row*DIM + c4);
      bf16x4 pk; pk[0]=(bf16)v.x; pk[1]=(bf16)v.y; pk[2]=(bf16)v.z; pk[3]=(bf16)v.w;
      *(bf16x4*)&sA[row*SXP + c4] = pk;
    }
    for (int i = tid; i < 14*32; i += 256) {
      int row = NTOK + (i >> 5), c4 = (i & 31) << 2;
      uint2 z; z.x = 0; z.y = 0;
      *(uint2*)&sA[row*SXP + c4] = z;
    }
  }
  __syncthreads();

  bf16* stg = sB + h*HREG;
  bf16x8 bk[7], aq[7], bv[2][4];

  // ---- phase 1ab: K + Q fragments (merged, d-interleaved packed stores) ----
  {
    const int baseK = DIM + h*HD, baseQ = h*HD;
    bf16x8 wK0[4], wK1[4], wQ0[4], wQ1[4];
#pragma unroll
    for (int ks = 0; ks < 4; ++ks) {
      wK0[ks] = *(const bf16x8*)(WTq + (baseK + l16)*DIM + ks*32 + quad*8);
      wK1[ks] = *(const bf16x8*)(WTq + (baseK + 16 + l16)*DIM + ks*32 + quad*8);
      wQ0[ks] = *(const bf16x8*)(WTq + (baseQ + l16)*DIM + ks*32 + quad*8);
      wQ1[ks] = *(const bf16x8*)(WTq + (baseQ + 16 + l16)*DIM + ks*32 + quad*8);
    }
    const float cK0 = qkv_b[baseK + l16], cK1 = qkv_b[baseK + 16 + l16];
    const float cQ0 = qkv_b[baseQ + l16], cQ1 = qkv_b[baseQ + 16 + l16];
#pragma unroll
    for (int mt = 0; mt < 7; ++mt) {
      f32x4 k0 = fzero, k1 = fzero, q0 = fzero, q1 = fzero;
#pragma unroll
      for (int ks = 0; ks < 4; ++ks) {
        const bf16x8 a = *(const bf16x8*)&sA[(mt*16 + l16)*SXP + ks*32 + quad*8];
        k0 = __builtin_amdgcn_mfma_f32_16x16x32_bf16(a, wK0[ks], k0, 0, 0, 0);
        k1 = __builtin_amdgcn_mfma_f32_16x16x32_bf16(a, wK1[ks], k1, 0, 0, 0);
        q0 = __builtin_amdgcn_mfma_f32_16x16x32_bf16(a, wQ0[ks], q0, 0, 0, 0);
        q1 = __builtin_amdgcn_mfma_f32_16x16x32_bf16(a, wQ1[ks], q1, 0, 0, 0);
      }
#pragma unroll
      for (int r = 0; r < 4; ++r) {
        bf16x2 pk; pk[0] = (bf16)(k0[r] + cK0); pk[1] = (bf16)(k1[r] + cK1);
        *(bf16x2*)&stg[(quad*4 + r)*STGP + l16*2] = pk;
        bf16x2 pq; pq[0] = (bf16)((q0[r] + cQ0) * SCALE_Q2);
        pq[1] = (bf16)((q1[r] + cQ1) * SCALE_Q2);
        *(bf16x2*)&stg[(16 + quad*4 + r)*STGP + l16*2] = pq;
      }
      bk[mt] = *(const bf16x8*)&stg[l16*STGP + quad*8];
      aq[mt] = *(const bf16x8*)&stg[(16 + l16)*STGP + quad*8];
    }
  }

  // ---- phase 1c: V^T fragments (natural token order) ----
  {
    const int baseV = 2*DIM + h*HD;
    bf16x8 wV0[4], wV1[4];
#pragma unroll
    for (int ks = 0; ks < 4; ++ks) {
      wV0[ks] = *(const bf16x8*)(WTq + (baseV + l16)*DIM + ks*32 + quad*8);
      wV1[ks] = *(const bf16x8*)(WTq + (baseV + 16 + l16)*DIM + ks*32 + quad*8);
    }
    const float cV0 = qkv_b[baseV + l16], cV1 = qkv_b[baseV + 16 + l16];
#pragma unroll
    for (int ck = 0; ck < 4; ++ck) {
      bf16* vb = stg + (ck & 1)*1280;
#pragma unroll
      for (int hf = 0; hf < 2; ++hf) {
        const int mt = ck*2 + hf;
        if (mt < 7) {
          f32x4 a0 = fzero, a1 = fzero;
#pragma unroll
          for (int ks = 0; ks < 4; ++ks) {
            const bf16x8 a = *(const bf16x8*)&sA[(mt*16 + l16)*SXP + ks*32 + quad*8];
            a0 = __builtin_amdgcn_mfma_f32_16x16x32_bf16(a, wV0[ks], a0, 0, 0, 0);
            a1 = __builtin_amdgcn_mfma_f32_16x16x32_bf16(a, wV1[ks], a1, 0, 0, 0);
          }
          bf16x4 p0, p1;
#pragma unroll
          for (int r = 0; r < 4; ++r) { p0[r] = (bf16)(a0[r] + cV0); p1[r] = (bf16)(a1[r] + cV1); }
          *(bf16x4*)&vb[l16*STGP + hf*16 + quad*4] = p0;
          *(bf16x4*)&vb[(16 + l16)*STGP + hf*16 + quad*4] = p1;
        } else {
          uint2 z; z.x = 0; z.y = 0;
          *(uint2*)&vb[l16*STGP + hf*16 + quad*4] = z;
          *(uint2*)&vb[(16 + l16)*STGP + hf*16 + quad*4] = z;
        }
      }
      bv[0][ck] = *(const bf16x8*)&vb[l16*STGP + quad*8];
      bv[1][ck] = *(const bf16x8*)&vb[(16 + l16)*STGP + quad*8];
    }
  }
  __syncthreads();   // all waves done reading x from sA; sA becomes O

  // ---- phase 2: attention, S^T orientation ----
  bf16* sP = stg;    // 16 x SPP, overlays dead staging
  {   // zero P pad cols 112..127 once
    int row = lane >> 2, c0 = 112 + ((lane & 3) << 2);
    uint2 z; z.x = 0; z.y = 0;
    *(uint2*)&sP[row*SPP + c0] = z;
  }
  const float* bmh = bmt + ((size_t)(w*4 + h))*(NP*NP);

#pragma unroll
  for (int mt = 0; mt < 7; ++mt) {
    // S^T[k][q]: lane owns q-row (mt*16+l16), k = nt*16 + quad*4 + r
    f32x4 s[7];
#pragma unroll
    for (int nt = 0; nt < 7; ++nt)
      s[nt] = __builtin_amdgcn_mfma_f32_16x16x32_bf16(bk[nt], aq[mt], fzero, 0, 0, 0);
    const float* bq = bmh + (mt*16 + l16)*NP;
#pragma unroll
    for (int nt = 0; nt < 7; ++nt) {
      const f32x4 bm4 = *(const f32x4*)(bq + nt*16 + quad*4);
      s[nt] = s[nt] + bm4;
    }
    // exp2 (native v_exp_f32; inputs pre-scaled by log2e; masked k -> 0)
#pragma unroll
    for (int nt = 0; nt < 7; ++nt)
#pragma unroll
      for (int r = 0; r < 4; ++r)
        s[nt][r] = __builtin_amdgcn_exp2f(s[nt][r]);
    // P-hat store (unnormalized), packed b64, natural k order
#pragma unroll
    for (int nt = 0; nt < 7; ++nt) {
      bf16x4 pk;
#pragma unroll
      for (int r = 0; r < 4; ++r) pk[r] = (bf16)s[nt][r];
      *(bf16x4*)&sP[l16*SPP + nt*16 + quad*4] = pk;
    }
    // O-tile = P-hat V issued first; the sum/shuffle chain runs concurrently
    f32x4 o0 = fzero, o1 = fzero;
#pragma unroll
    for (int ks = 0; ks < 4; ++ks) {
      const bf16x8 ap = *(const bf16x8*)&sP[l16*SPP + ks*32 + quad*8];
      o0 = __builtin_amdgcn_mfma_f32_16x16x32_bf16(ap, bv[0][ks], o0, 0, 0, 0);
      o1 = __builtin_amdgcn_mfma_f32_16x16x32_bf16(ap, bv[1][ks], o1, 0, 0, 0);
    }
    // row sum for q = mt*16 + l16: in-register tree + 2 shuffles
    float rs[7];
#pragma unroll
    for (int nt = 0; nt < 7; ++nt)
      rs[nt] = (s[nt][0] + s[nt][1]) + (s[nt][2] + s[nt][3]);
    float sum = ((rs[0] + rs[1]) + (rs[2] + rs[3])) + ((rs[4] + rs[5]) + rs[6]);
    sum += __shfl_xor(sum, 16);
    sum += __shfl_xor(sum, 32);
    const float inv = __builtin_amdgcn_rcpf(sum);   // inv for q-row = mt*16 + l16
    // PV output rows are q = mt*16 + quad*4 + r -> transpose inv via shuffles
    float invr[4];
#pragma unroll
    for (int r = 0; r < 4; ++r)
      invr[r] = __shfl(inv, quad*4 + r, 64);
#pragma unroll
    for (int r = 0; r < 4; ++r) {
      bf16x2 ow; ow[0] = (bf16)(o0[r]*invr[r]); ow[1] = (bf16)(o1[r]*invr[r]);
      *(bf16x2*)&sA[(mt*16 + quad*4 + r)*SXP + h*HD + l16*2] = ow;
    }
  }
  __syncthreads();

  // ---- phase 3: proj GEMM from sA(O, interleaved) with PT2; waves do col-tiles {wave, wave+4}
  float* outb = out + (size_t)b * (NTOK*DIM);
#pragma unroll
  for (int nn = 0; nn < 2; ++nn) {
    const int nt2 = wave + nn*4;
    bf16x8 pf[4];
#pragma unroll
    for (int ks = 0; ks < 4; ++ks)
      pf[ks] = *(const bf16x8*)(PT2 + (nt2*16 + l16)*DIM + ks*32 + quad*8);
    const float pb = proj_b[nt2*16 + l16];
#pragma unroll
    for (int mt = 0; mt < 7; ++mt) {
      f32x4 acc = fzero;
#pragma unroll
      for (int ks = 0; ks < 4; ++ks) {
        const bf16x8 a = *(const bf16x8*)&sA[(mt*16 + l16)*SXP + ks*32 + quad*8];
        acc = __builtin_amdgcn_mfma_f32_16x16x32_bf16(a, pf[ks], acc, 0, 0, 0);
      }
#pragma unroll
      for (int r = 0; r < 4; ++r) {
        const int row = mt*16 + quad*4 + r;
        if (row < NTOK)
          outb[row*DIM + nt2*16 + l16] = acc[r] + pb;
      }
    }
  }
}

// ===================== fallback path (used if ws too small) =====================

__global__ __launch_bounds__(256) void prep_kernel(
    const float* __restrict__ qkv_w, const float* __restrict__ proj_w,
    const float* __restrict__ table, const int* __restrict__ rel_index,
    bf16* __restrict__ WTq, bf16* __restrict__ PT, float* __restrict__ biasf)
{
  int i = blockIdx.x * 256 + threadIdx.x;
  if (i < 384*128) {
    int n = i >> 7, k = i & 127;
    WTq[i] = (bf16)qkv_w[k*384 + n];
  } else if (i < 384*128 + 128*128) {
    int j = i - 384*128; int n = j >> 7, k = j & 127;
    PT[j] = (bf16)proj_w[k*128 + n];
  } else if (i < 384*128 + 128*128 + 98*98) {
    int j = i - (384*128 + 128*128);
    int idx = rel_index[j];
#pragma unroll
    for (int h = 0; h < 4; ++h) biasf[h*9604 + j] = table[idx*4 + h];
  }
}

__global__ __launch_bounds__(512, 2) void win_attn_kernel(
    const float* __restrict__ x, const float* __restrict__ mask,
    const float* __restrict__ qkv_b, const float* __restrict__ proj_b,
    const bf16* __restrict__ WTq, const bf16* __restrict__ PT,
    const float* __restrict__ biasf, float* __restrict__ out)
{
  __shared__ bf16 sX[NP*SXP];
  __shared__ bf16 sK[NH*NP*SKP];
  __shared__ bf16 sVT[NH*HD*SVP];
  __shared__ bf16 sQs[8*16*SQP];
  __shared__ bf16 sPs[8*16*SPP];

  const int b = blockIdx.x;
  const int w = b & 63;
  const int tid = threadIdx.x;
  const int wave = tid >> 6, lane = tid & 63;
  const int quad = lane >> 4, l16 = lane & 15;
  const f32x4 fzero = {0.f, 0.f, 0.f, 0.f};

  {
    const float* xb = x + (size_t)b * (NTOK*DIM);
    for (int i = tid; i < NTOK*32; i += 512) {
      int row = i >> 5, c4 = (i & 31) << 2;
      const float4 v = *(const float4*)(xb + row*DIM + c4);
      bf16x4 pk; pk[0]=(bf16)v.x; pk[1]=(bf16)v.y; pk[2]=(bf16)v.z; pk[3]=(bf16)v.w;
      *(bf16x4*)&sX[row*SXP + c4] = pk;
    }
    for (int i = tid; i < 14*32; i += 512) {
      int row = NTOK + (i >> 5), c4 = (i & 31) << 2;
      uint2 z; z.x = 0; z.y = 0;
      *(uint2*)&sX[row*SXP + c4] = z;
    }
    {
      int h = tid >> 7, rem = tid & 127, d = rem >> 2, c0 = 112 + ((rem & 3) << 2);
      uint2 z; z.x = 0; z.y = 0;
      *(uint2*)&sVT[(h*HD + d)*SVP + c0] = z;
    }
  }
  __syncthreads();

#pragma unroll
  for (int j = 0; j < 2; ++j) {
    const int job = wave*2 + j;
    const int h = job >> 2, part = job & 3;
    const bool isK = part < 2;
    const int ncol = (isK ? DIM + h*HD + part*16 : 2*DIM + h*HD + (part-2)*16) + l16;
    bf16x8 bfr[4];
#pragma unroll
    for (int ks = 0; ks < 4; ++ks)
      bfr[ks] = *(const bf16x8*)(WTq + ncol*DIM + ks*32 + quad*8);
    const float cb = qkv_b[ncol];
#pragma unroll
    for (int mt = 0; mt < 7; ++mt) {
      f32x4 acc = fzero;
#pragma unroll
      for (int ks = 0; ks < 4; ++ks) {
        const bf16x8 a = *(const bf16x8*)&sX[(mt*16 + l16)*SXP + ks*32 + quad*8];
        acc = __builtin_amdgcn_mfma_f32_16x16x32_bf16(a, bfr[ks], acc, 0, 0, 0);
      }
      const int tb = mt*16 + quad*4;
      if (isK) {
        const int d = part*16 + l16;
#pragma unroll
        for (int r = 0; r < 4; ++r)
          sK[(h*NP + tb + r)*SKP + d] = (bf16)(acc[r] + cb);
      } else {
        const int d = (part-2)*16 + l16;
        bf16x4 pk;
#pragma unroll
        for (int r = 0; r < 4; ++r) pk[r] = (bf16)(acc[r] + cb);
        *(bf16x4*)&sVT[(h*HD + d)*SVP + tb] = pk;
      }
    }
  }
  __syncthreads();

  {
    const int h = wave >> 1, sub = wave & 1;
    bf16x8 qb[2][4];
#pragma unroll
    for (int nt2 = 0; nt2 < 2; ++nt2)
#pragma unroll
      for (int ks = 0; ks < 4; ++ks)
        qb[nt2][ks] = *(const bf16x8*)(WTq + (h*HD + nt2*16 + l16)*DIM + ks*32 + quad*8);
    const float qbias0 = qkv_b[h*HD + l16];
    const float qbias1 = qkv_b[h*HD + 16 + l16];
    bf16* sQ = sQs + wave*16*SQP;
    bf16* sP = sPs + wave*16*SPP;
    {
      int row = lane >> 2, c0 = 112 + ((lane & 3) << 2);
      uint2 z; z.x = 0; z.y = 0;
      *(uint2*)&sP[row*SPP + c0] = z;
    }
    const float* bias_h = biasf + h*9604;
    const float* mask_w = mask + w*9604;

    f32x4 oacc0 = fzero, oacc1 = fzero;
#pragma unroll 1
    for (int it = 0; it < 4; ++it) {
      const int mt = sub + it*2;
      const bool valid = mt < 7;
      if (valid) {
        f32x4 qa0 = fzero, qa1 = fzero;
#pragma unroll
        for (int ks = 0; ks < 4; ++ks) {
          const bf16x8 a = *(const bf16x8*)&sX[(mt*16 + l16)*SXP + ks*32 + quad*8];
          qa0 = __builtin_amdgcn_mfma_f32_16x16x32_bf16(a, qb[0][ks], qa0, 0, 0, 0);
          qa1 = __builtin_amdgcn_mfma_f32_16x16x32_bf16(a, qb[1][ks], qa1, 0, 0, 0);
        }
#pragma unroll
        for (int r = 0; r < 4; ++r) {
          sQ[(quad*4 + r)*SQP + l16]      = (bf16)((qa0[r] + qbias0) * SCALE_Q);
          sQ[(quad*4 + r)*SQP + 16 + l16] = (bf16)((qa1[r] + qbias1) * SCALE_Q);
        }
        const bf16x8 aq = *(const bf16x8*)&sQ[l16*SQP + quad*8];
        f32x4 s[7];
#pragma unroll
        for (int nt = 0; nt < 7; ++nt) {
          const bf16x8 bk2 = *(const bf16x8*)&sK[(h*NP + nt*16 + l16)*SKP + quad*8];
          s[nt] = __builtin_amdgcn_mfma_f32_16x16x32_bf16(aq, bk2, fzero, 0, 0, 0);
        }
#pragma unroll
        for (int r = 0; r < 4; ++r) {
          const int row = mt*16 + quad*4 + r;
          const bool rowok = row < NTOK;
          float mx = -3.0e38f;
#pragma unroll
          for (int nt = 0; nt < 7; ++nt) {
            const int col = nt*16 + l16;
            float sv;
            if (rowok && col < NTOK)
              sv = s[nt][r] + bias_h[row*NTOK + col] + mask_w[row*NTOK + col];
            else
              sv = -1.0e30f;
            s[nt][r] = sv;
            mx = fmaxf(mx, sv);
          }
#pragma unroll
          for (int off = 1; off < 16; off <<= 1)
            mx = fmaxf(mx, __shfl_xor(mx, off, 64));
          float sum = 0.f;
#pragma unroll
          for (int nt = 0; nt < 7; ++nt) {
            const float p = __expf(s[nt][r] - mx);
            s[nt][r] = p;
            sum += p;
          }
#pragma unroll
          for (int off = 1; off < 16; off <<= 1)
            sum += __shfl_xor(sum, off, 64);
          const float inv = __builtin_amdgcn_rcpf(sum);
#pragma unroll
          for (int nt = 0; nt < 7; ++nt)
            sP[(quad*4 + r)*SPP + nt*16 + l16] = (bf16)(s[nt][r] * inv);
        }
        oacc0 = fzero; oacc1 = fzero;
#pragma unroll
        for (int ks = 0; ks < 4; ++ks) {
          const bf16x8 ap = *(const bf16x8*)&sP[l16*SPP + ks*32 + quad*8];
          const bf16x8 bv0 = *(const bf16x8*)&sVT[(h*HD + l16)*SVP + ks*32 + quad*8];
          const bf16x8 bv1 = *(const bf16x8*)&sVT[(h*HD + 16 + l16)*SVP + ks*32 + quad*8];
          oacc0 = __builtin_amdgcn_mfma_f32_16x16x32_bf16(ap, bv0, oacc0, 0, 0, 0);
          oacc1 = __builtin_amdgcn_mfma_f32_16x16x32_bf16(ap, bv1, oacc1, 0, 0, 0);
        }
      }
      __syncthreads();
      if (valid) {
#pragma unroll
        for (int r = 0; r < 4; ++r) {
          sX[(mt*16 + quad*4 + r)*SXP + h*HD + l16]      = (bf16)(oacc0[r]);
          sX[(mt*16 + quad*4 + r)*SXP + h*HD + 16 + l16] = (bf16)(oacc1[r]);
        }
      }
    }
  }
  __syncthreads();

  {
    const int nt = wave;
    bf16x8 pbf[4];
#pragma unroll
    for (int ks = 0; ks < 4; ++ks)
      pbf[ks] = *(const bf16x8*)(PT + (nt*16 + l16)*DIM + ks*32 + quad*8);
    const float pb = proj_b[nt*16 + l16];
    float* outb = out + (size_t)b * (NTOK*DIM);
#pragma unroll
    for (int mt = 0; mt < 7; ++mt) {
      f32x4 acc = fzero;
#pragma unroll
      for (int ks = 0; ks < 4; ++ks) {
        const bf16x8 a = *(const bf16x8*)&sX[(mt*16 + l16)*SXP + ks*32 + quad*8];
        acc = __builtin_amdgcn_mfma_f32_16x16x32_bf16(a, pbf[ks], acc, 0, 0, 0);
      }
#pragma unroll
      for (int r = 0; r < 4; ++r) {
        const int row = mt*16 + quad*4 + r;
        if (row < NTOK)
          outb[row*DIM + nt*16 + l16] = acc[r] + pb;
      }
    }
  }
}

extern "C" void kernel_launch(void* const* d_in, const int* in_sizes, int n_in,
                              void* d_out, int out_size, void* d_ws, size_t ws_size,
                              hipStream_t stream)
{
  const float* x      = (const float*)d_in[0];
  const float* mask   = (const float*)d_in[1];
  const float* qkv_w  = (const float*)d_in[2];
  const float* qkv_b  = (const float*)d_in[3];
  const float* table  = (const float*)d_in[4];
  const int*   rel    = (const int*)d_in[5];
  const float* proj_w = (const float*)d_in[6];
  const float* proj_b = (const float*)d_in[7];
  float* out = (float*)d_out;
  char* ws = (char*)d_ws;

  if (ws_size >= WS_NEED) {
    bf16*  WTq = (bf16*)(ws + WS_WTQ);
    bf16*  PT2 = (bf16*)(ws + WS_PT);
    float* bmt = (float*)(ws + WS_BM);

    const int prep_total = PREP_SCALAR + PREP_BM_V4;   // 868352
    prep3_kernel<<<(prep_total + 255)/256, 256, 0, stream>>>(
        qkv_w, proj_w, table, rel, mask, WTq, PT2, bmt);
    fused_kernel<<<2048, 256, 0, stream>>>(x, qkv_b, proj_b, WTq, PT2, bmt, out);
  } else {
    bf16*  WTq   = (bf16*)(ws + WS_WTQ);
    bf16*  PT    = (bf16*)(ws + WS_PT);
    float* biasf = (float*)(ws + WS_BM);
    const int prep_total = 384*128 + 128*128 + 98*98;
    prep_kernel<<<(prep_total + 255)/256, 256, 0, stream>>>(qkv_w, proj_w, table, rel, WTq, PT, biasf);
    win_attn_kernel<<<2048, 512, 0, stream>>>(x, mask, qkv_b, proj_b, WTq, PT, biasf, out);
  }
}

// Round 7
// 267.688 us; speedup vs baseline: 1.1481x; 1.0467x over previous
//
#include <hip/hip_runtime.h>
#include <hip/hip_bf16.h>

typedef __bf16 bf16;
typedef __attribute__((ext_vector_type(8))) __bf16 bf16x8;
typedef __attribute__((ext_vector_type(4))) __bf16 bf16x4;
typedef __attribute__((ext_vector_type(2))) __bf16 bf16x2;
typedef __attribute__((ext_vector_type(4))) float f32x4;

#define NTOK 98
#define NP   112
#define DIM  128
#define NH   4
#define HD   32
#define LOG2E 1.4426950408889634f
// SCALE_Q * log2(e): scores arrive pre-scaled for exp2
#define SCALE_Q2 (0.17677669529663687f * 1.4426950408889634f)
#define SCALE_Q 0.17677669529663687f

#define SXP 136
#define SKP 40
#define SVP 136
#define SPP 136
#define SQP 40
#define STGP 40          // staging pitch (elems)
#define HREG 2560        // per-head staging region (elems) = 2 x 32 x STGP

// ---- fast-path ws layout (bytes) ----
#define WS_WTQ   0ULL                   // bf16 [384][128]            98304
#define WS_PT    98304ULL               // bf16 [128][128]            32768
#define WS_BM    131072ULL              // f32  [64][4][112][112]  12845056
#define WS_BIAS  12976128ULL            // f32  [4][112][112]        200704
#define WS_NEED  13176832ULL

#define PREPA_SCALAR (384*128 + 128*128)   // 65536
#define PREPA_BIAS   (4*112*28)            // 12544 (4 k per item)
#define PREPB_TOTAL  (64*4*112*28)         // 802816 (4 k per item)

// ===================== prep_a: transposes + one-shot bias gather =====================
// WTq[n][k] = qkv_w[k][n]
// PT2[n][j] = proj_w[nat(j)][n], nat de-interleaves the O store layout
// biasT[h][q 112][k 112] = table[rel[q,k],h]*log2e; k>=98 -> -1e30; q>=98 -> 0.
// The 98x98 gather is done ONCE here (prep3 used to redo it 64x, once per w).
__global__ __launch_bounds__(256) void prep_a_kernel(
    const float* __restrict__ qkv_w, const float* __restrict__ proj_w,
    const float* __restrict__ table, const int* __restrict__ rel,
    bf16* __restrict__ WTq, bf16* __restrict__ PT2, float* __restrict__ biasT)
{
  int i = blockIdx.x * 256 + threadIdx.x;
  if (i < 384*128) {
    int n = i >> 7, k = i & 127;
    WTq[i] = (bf16)qkv_w[k*384 + n];
  } else if (i < PREPA_SCALAR) {
    int j = i - 384*128; int n = j >> 7, kp = j & 127;
    int blk = kp >> 5, jl = kp & 31;
    int dl = (jl >> 1) + 16*(jl & 1);
    PT2[j] = (bf16)proj_w[(blk*32 + dl)*128 + n];
  } else {
    int g = i - PREPA_SCALAR;
    if (g >= PREPA_BIAS) return;
    int k4 = (g % 28) * 4;
    int rest = g / 28;
    int q = rest % 112;
    int h = rest / 112;
    f32x4 v;
#pragma unroll
    for (int j = 0; j < 4; ++j) {
      int k = k4 + j;
      if (q >= NTOK)      v[j] = 0.f;
      else if (k >= NTOK) v[j] = -1.0e30f;
      else                v[j] = table[rel[q*98 + k]*4 + h] * LOG2E;
    }
    *(f32x4*)(biasT + (h*NP + q)*NP + k4) = v;
  }
}

// ===================== prep_b: pure streaming broadcast-add =====================
// bmt[w][h][q][k] = biasT[h][q][k] + mask[w][q][k]*log2e (guarded). No gathers.
__global__ __launch_bounds__(256) void prep_b_kernel(
    const float* __restrict__ mask, const float* __restrict__ biasT,
    float* __restrict__ bmt)
{
  int g = blockIdx.x * 256 + threadIdx.x;
  if (g >= PREPB_TOTAL) return;
  int k4 = (g % 28) * 4;
  int rest = g / 28;
  int q = rest % 112;
  int rest2 = rest / 112;
  int h = rest2 & 3;
  int w = rest2 >> 2;
  f32x4 v = *(const f32x4*)(biasT + (h*NP + q)*NP + k4);
  if (q < NTOK) {
    const float* mrow = mask + w*9604 + q*98;
#pragma unroll
    for (int j = 0; j < 4; ++j) {
      int k = k4 + j;
      if (k < NTOK) v[j] = fmaf(mrow[k], LOG2E, v[j]);
    }
  }
  *(f32x4*)(bmt + ((size_t)(w*4 + h))*(NP*NP) + q*NP + k4) = v;
}

// ===================== fused qkv + attention + proj =====================
// One block per window. 4 waves, wave = head. Q/K/V stay on-chip.
// S^T orientation: s = mfma(K,Q) -> lane owns scores of q-row (mt*16+l16).
// bias+mask folded into the QK MFMA as C-in (load precedes MFMA in the dep
// graph; deletes the post-add pass). exp2-native softmax, no max-subtract,
// normalization deferred to the O-write (inv transposed via lane shuffles).
// r5 lesson: no cross-iteration register prefetch (spilled at the 170-VGPR
// cap for 3 waves/SIMD).
__global__ __launch_bounds__(256, 3) void fused_kernel(
    const float* __restrict__ x, const float* __restrict__ qkv_b,
    const float* __restrict__ proj_b,
    const bf16* __restrict__ WTq, const bf16* __restrict__ PT2,
    const float* __restrict__ bmt, float* __restrict__ out)
{
  __shared__ alignas(16) bf16 sA[NP*SXP];      // x staged -> later O
  __shared__ alignas(16) bf16 sB[4*HREG];      // per-head staging -> later P

  const int b = blockIdx.x, w = b & 63;
  const int tid = threadIdx.x;
  const int wave = tid >> 6, lane = tid & 63;
  const int quad = lane >> 4, l16 = lane & 15;
  const int h = wave;
  const f32x4 fzero = {0.f, 0.f, 0.f, 0.f};

  // ---- phase 0: stage x -> sA (bf16, rows 98..111 zero) ----
  {
    const float* xb = x + (size_t)b * (NTOK*DIM);
    for (int i = tid; i < NTOK*32; i += 256) {
      int row = i >> 5, c4 = (i & 31) << 2;
      const float4 v = *(const float4*)(xb + row*DIM + c4);
      bf16x4 pk; pk[0]=(bf16)v.x; pk[1]=(bf16)v.y; pk[2]=(bf16)v.z; pk[3]=(bf16)v.w;
      *(bf16x4*)&sA[row*SXP + c4] = pk;
    }
    for (int i = tid; i < 14*32; i += 256) {
      int row = NTOK + (i >> 5), c4 = (i & 31) << 2;
      uint2 z; z.x = 0; z.y = 0;
      *(uint2*)&sA[row*SXP + c4] = z;
    }
  }
  __syncthreads();

  bf16* stg = sB + h*HREG;
  bf16x8 bk[7], aq[7], bv[2][4];

  // ---- phase 1ab: K + Q fragments (merged, d-interleaved packed stores) ----
  {
    const int baseK = DIM + h*HD, baseQ = h*HD;
    bf16x8 wK0[4], wK1[4], wQ0[4], wQ1[4];
#pragma unroll
    for (int ks = 0; ks < 4; ++ks) {
      wK0[ks] = *(const bf16x8*)(WTq + (baseK + l16)*DIM + ks*32 + quad*8);
      wK1[ks] = *(const bf16x8*)(WTq + (baseK + 16 + l16)*DIM + ks*32 + quad*8);
      wQ0[ks] = *(const bf16x8*)(WTq + (baseQ + l16)*DIM + ks*32 + quad*8);
      wQ1[ks] = *(const bf16x8*)(WTq + (baseQ + 16 + l16)*DIM + ks*32 + quad*8);
    }
    const float cK0 = qkv_b[baseK + l16], cK1 = qkv_b[baseK + 16 + l16];
    const float cQ0 = qkv_b[baseQ + l16], cQ1 = qkv_b[baseQ + 16 + l16];
#pragma unroll
    for (int mt = 0; mt < 7; ++mt) {
      f32x4 k0 = fzero, k1 = fzero, q0 = fzero, q1 = fzero;
#pragma unroll
      for (int ks = 0; ks < 4; ++ks) {
        const bf16x8 a = *(const bf16x8*)&sA[(mt*16 + l16)*SXP + ks*32 + quad*8];
        k0 = __builtin_amdgcn_mfma_f32_16x16x32_bf16(a, wK0[ks], k0, 0, 0, 0);
        k1 = __builtin_amdgcn_mfma_f32_16x16x32_bf16(a, wK1[ks], k1, 0, 0, 0);
        q0 = __builtin_amdgcn_mfma_f32_16x16x32_bf16(a, wQ0[ks], q0, 0, 0, 0);
        q1 = __builtin_amdgcn_mfma_f32_16x16x32_bf16(a, wQ1[ks], q1, 0, 0, 0);
      }
#pragma unroll
      for (int r = 0; r < 4; ++r) {
        bf16x2 pk; pk[0] = (bf16)(k0[r] + cK0); pk[1] = (bf16)(k1[r] + cK1);
        *(bf16x2*)&stg[(quad*4 + r)*STGP + l16*2] = pk;
        bf16x2 pq; pq[0] = (bf16)((q0[r] + cQ0) * SCALE_Q2);
        pq[1] = (bf16)((q1[r] + cQ1) * SCALE_Q2);
        *(bf16x2*)&stg[(16 + quad*4 + r)*STGP + l16*2] = pq;
      }
      bk[mt] = *(const bf16x8*)&stg[l16*STGP + quad*8];
      aq[mt] = *(const bf16x8*)&stg[(16 + l16)*STGP + quad*8];
    }
  }

  // ---- phase 1c: V^T fragments (natural token order) ----
  {
    const int baseV = 2*DIM + h*HD;
    bf16x8 wV0[4], wV1[4];
#pragma unroll
    for (int ks = 0; ks < 4; ++ks) {
      wV0[ks] = *(const bf16x8*)(WTq + (baseV + l16)*DIM + ks*32 + quad*8);
      wV1[ks] = *(const bf16x8*)(WTq + (baseV + 16 + l16)*DIM + ks*32 + quad*8);
    }
    const float cV0 = qkv_b[baseV + l16], cV1 = qkv_b[baseV + 16 + l16];
#pragma unroll
    for (int ck = 0; ck < 4; ++ck) {
      bf16* vb = stg + (ck & 1)*1280;
#pragma unroll
      for (int hf = 0; hf < 2; ++hf) {
        const int mt = ck*2 + hf;
        if (mt < 7) {
          f32x4 a0 = fzero, a1 = fzero;
#pragma unroll
          for (int ks = 0; ks < 4; ++ks) {
            const bf16x8 a = *(const bf16x8*)&sA[(mt*16 + l16)*SXP + ks*32 + quad*8];
            a0 = __builtin_amdgcn_mfma_f32_16x16x32_bf16(a, wV0[ks], a0, 0, 0, 0);
            a1 = __builtin_amdgcn_mfma_f32_16x16x32_bf16(a, wV1[ks], a1, 0, 0, 0);
          }
          bf16x4 p0, p1;
#pragma unroll
          for (int r = 0; r < 4; ++r) { p0[r] = (bf16)(a0[r] + cV0); p1[r] = (bf16)(a1[r] + cV1); }
          *(bf16x4*)&vb[l16*STGP + hf*16 + quad*4] = p0;
          *(bf16x4*)&vb[(16 + l16)*STGP + hf*16 + quad*4] = p1;
        } else {
          uint2 z; z.x = 0; z.y = 0;
          *(uint2*)&vb[l16*STGP + hf*16 + quad*4] = z;
          *(uint2*)&vb[(16 + l16)*STGP + hf*16 + quad*4] = z;
        }
      }
      bv[0][ck] = *(const bf16x8*)&vb[l16*STGP + quad*8];
      bv[1][ck] = *(const bf16x8*)&vb[(16 + l16)*STGP + quad*8];
    }
  }
  __syncthreads();   // all waves done reading x from sA; sA becomes O

  // ---- phase 2: attention, S^T orientation ----
  bf16* sP = stg;    // 16 x SPP, overlays dead staging
  {   // zero P pad cols 112..127 once
    int row = lane >> 2, c0 = 112 + ((lane & 3) << 2);
    uint2 z; z.x = 0; z.y = 0;
    *(uint2*)&sP[row*SPP + c0] = z;
  }
  const float* bmh = bmt + ((size_t)(w*4 + h))*(NP*NP);

#pragma unroll
  for (int mt = 0; mt < 7; ++mt) {
    // S^T[k][q]: lane owns q-row (mt*16+l16), k = nt*16 + quad*4 + r.
    // bias+mask ride in as the MFMA C operand.
    const float* bq = bmh + (mt*16 + l16)*NP;
    f32x4 s[7];
#pragma unroll
    for (int nt = 0; nt < 7; ++nt) {
      const f32x4 bm4 = *(const f32x4*)(bq + nt*16 + quad*4);
      s[nt] = __builtin_amdgcn_mfma_f32_16x16x32_bf16(bk[nt], aq[mt], bm4, 0, 0, 0);
    }
    // exp2 (native v_exp_f32; inputs pre-scaled by log2e; masked k -> 0)
#pragma unroll
    for (int nt = 0; nt < 7; ++nt)
#pragma unroll
      for (int r = 0; r < 4; ++r)
        s[nt][r] = __builtin_amdgcn_exp2f(s[nt][r]);
    // P-hat store (unnormalized), packed b64, natural k order
#pragma unroll
    for (int nt = 0; nt < 7; ++nt) {
      bf16x4 pk;
#pragma unroll
      for (int r = 0; r < 4; ++r) pk[r] = (bf16)s[nt][r];
      *(bf16x4*)&sP[l16*SPP + nt*16 + quad*4] = pk;
    }
    // O-tile = P-hat V issued first; the sum/shuffle chain runs concurrently
    f32x4 o0 = fzero, o1 = fzero;
#pragma unroll
    for (int ks = 0; ks < 4; ++ks) {
      const bf16x8 ap = *(const bf16x8*)&sP[l16*SPP + ks*32 + quad*8];
      o0 = __builtin_amdgcn_mfma_f32_16x16x32_bf16(ap, bv[0][ks], o0, 0, 0, 0);
      o1 = __builtin_amdgcn_mfma_f32_16x16x32_bf16(ap, bv[1][ks], o1, 0, 0, 0);
    }
    // row sum for q = mt*16 + l16: in-register tree + 2 shuffles
    float rs[7];
#pragma unroll
    for (int nt = 0; nt < 7; ++nt)
      rs[nt] = (s[nt][0] + s[nt][1]) + (s[nt][2] + s[nt][3]);
    float sum = ((rs[0] + rs[1]) + (rs[2] + rs[3])) + ((rs[4] + rs[5]) + rs[6]);
    sum += __shfl_xor(sum, 16);
    sum += __shfl_xor(sum, 32);
    const float inv = __builtin_amdgcn_rcpf(sum);   // inv for q-row = mt*16 + l16
    // PV output rows are q = mt*16 + quad*4 + r -> transpose inv via shuffles
    float invr[4];
#pragma unroll
    for (int r = 0; r < 4; ++r)
      invr[r] = __shfl(inv, quad*4 + r, 64);
#pragma unroll
    for (int r = 0; r < 4; ++r) {
      bf16x2 ow; ow[0] = (bf16)(o0[r]*invr[r]); ow[1] = (bf16)(o1[r]*invr[r]);
      *(bf16x2*)&sA[(mt*16 + quad*4 + r)*SXP + h*HD + l16*2] = ow;
    }
  }
  __syncthreads();

  // ---- phase 3: proj GEMM from sA(O, interleaved) with PT2; waves do col-tiles {wave, wave+4}
  float* outb = out + (size_t)b * (NTOK*DIM);
#pragma unroll
  for (int nn = 0; nn < 2; ++nn) {
    const int nt2 = wave + nn*4;
    bf16x8 pf[4];
#pragma unroll
    for (int ks = 0; ks < 4; ++ks)
      pf[ks] = *(const bf16x8*)(PT2 + (nt2*16 + l16)*DIM + ks*32 + quad*8);
    const float pb = proj_b[nt2*16 + l16];
#pragma unroll
    for (int mt = 0; mt < 7; ++mt) {
      f32x4 acc = fzero;
#pragma unroll
      for (int ks = 0; ks < 4; ++ks) {
        const bf16x8 a = *(const bf16x8*)&sA[(mt*16 + l16)*SXP + ks*32 + quad*8];
        acc = __builtin_amdgcn_mfma_f32_16x16x32_bf16(a, pf[ks], acc, 0, 0, 0);
      }
#pragma unroll
      for (int r = 0; r < 4; ++r) {
        const int row = mt*16 + quad*4 + r;
        if (row < NTOK)
          outb[row*DIM + nt2*16 + l16] = acc[r] + pb;
      }
    }
  }
}

// ===================== fallback path (used if ws too small) =====================

__global__ __launch_bounds__(256) void prep_kernel(
    const float* __restrict__ qkv_w, const float* __restrict__ proj_w,
    const float* __restrict__ table, const int* __restrict__ rel_index,
    bf16* __restrict__ WTq, bf16* __restrict__ PT, float* __restrict__ biasf)
{
  int i = blockIdx.x * 256 + threadIdx.x;
  if (i < 384*128) {
    int n = i >> 7, k = i & 127;
    WTq[i] = (bf16)qkv_w[k*384 + n];
  } else if (i < 384*128 + 128*128) {
    int j = i - 384*128; int n = j >> 7, k = j & 127;
    PT[j] = (bf16)proj_w[k*128 + n];
  } else if (i < 384*128 + 128*128 + 98*98) {
    int j = i - (384*128 + 128*128);
    int idx = rel_index[j];
#pragma unroll
    for (int h = 0; h < 4; ++h) biasf[h*9604 + j] = table[idx*4 + h];
  }
}

__global__ __launch_bounds__(512, 2) void win_attn_kernel(
    const float* __restrict__ x, const float* __restrict__ mask,
    const float* __restrict__ qkv_b, const float* __restrict__ proj_b,
    const bf16* __restrict__ WTq, const bf16* __restrict__ PT,
    const float* __restrict__ biasf, float* __restrict__ out)
{
  __shared__ bf16 sX[NP*SXP];
  __shared__ bf16 sK[NH*NP*SKP];
  __shared__ bf16 sVT[NH*HD*SVP];
  __shared__ bf16 sQs[8*16*SQP];
  __shared__ bf16 sPs[8*16*SPP];

  const int b = blockIdx.x;
  const int w = b & 63;
  const int tid = threadIdx.x;
  const int wave = tid >> 6, lane = tid & 63;
  const int quad = lane >> 4, l16 = lane & 15;
  const f32x4 fzero = {0.f, 0.f, 0.f, 0.f};

  {
    const float* xb = x + (size_t)b * (NTOK*DIM);
    for (int i = tid; i < NTOK*32; i += 512) {
      int row = i >> 5, c4 = (i & 31) << 2;
      const float4 v = *(const float4*)(xb + row*DIM + c4);
      bf16x4 pk; pk[0]=(bf16)v.x; pk[1]=(bf16)v.y; pk[2]=(bf16)v.z; pk[3]=(bf16)v.w;
      *(bf16x4*)&sX[row*SXP + c4] = pk;
    }
    for (int i = tid; i < 14*32; i += 512) {
      int row = NTOK + (i >> 5), c4 = (i & 31) << 2;
      uint2 z; z.x = 0; z.y = 0;
      *(uint2*)&sX[row*SXP + c4] = z;
    }
    {
      int h = tid >> 7, rem = tid & 127, d = rem >> 2, c0 = 112 + ((rem & 3) << 2);
      uint2 z; z.x = 0; z.y = 0;
      *(uint2*)&sVT[(h*HD + d)*SVP + c0] = z;
    }
  }
  __syncthreads();

#pragma unroll
  for (int j = 0; j < 2; ++j) {
    const int job = wave*2 + j;
    const int h = job >> 2, part = job & 3;
    const bool isK = part < 2;
    const int ncol = (isK ? DIM + h*HD + part*16 : 2*DIM + h*HD + (part-2)*16) + l16;
    bf16x8 bfr[4];
#pragma unroll
    for (int ks = 0; ks < 4; ++ks)
      bfr[ks] = *(const bf16x8*)(WTq + ncol*DIM + ks*32 + quad*8);
    const float cb = qkv_b[ncol];
#pragma unroll
    for (int mt = 0; mt < 7; ++mt) {
      f32x4 acc = fzero;
#pragma unroll
      for (int ks = 0; ks < 4; ++ks) {
        const bf16x8 a = *(const bf16x8*)&sX[(mt*16 + l16)*SXP + ks*32 + quad*8];
        acc = __builtin_amdgcn_mfma_f32_16x16x32_bf16(a, bfr[ks], acc, 0, 0, 0);
      }
      const int tb = mt*16 + quad*4;
      if (isK) {
        const int d = part*16 + l16;
#pragma unroll
        for (int r = 0; r < 4; ++r)
          sK[(h*NP + tb + r)*SKP + d] = (bf16)(acc[r] + cb);
      } else {
        const int d = (part-2)*16 + l16;
        bf16x4 pk;
#pragma unroll
        for (int r = 0; r < 4; ++r) pk[r] = (bf16)(acc[r] + cb);
        *(bf16x4*)&sVT[(h*HD + d)*SVP + tb] = pk;
      }
    }
  }
  __syncthreads();

  {
    const int h = wave >> 1, sub = wave & 1;
    bf16x8 qb[2][4];
#pragma unroll
    for (int nt2 = 0; nt2 < 2; ++nt2)
#pragma unroll
      for (int ks = 0; ks < 4; ++ks)
        qb[nt2][ks] = *(const bf16x8*)(WTq + (h*HD + nt2*16 + l16)*DIM + ks*32 + quad*8);
    const float qbias0 = qkv_b[h*HD + l16];
    const float qbias1 = qkv_b[h*HD + 16 + l16];
    bf16* sQ = sQs + wave*16*SQP;
    bf16* sP = sPs + wave*16*SPP;
    {
      int row = lane >> 2, c0 = 112 + ((lane & 3) << 2);
      uint2 z; z.x = 0; z.y = 0;
      *(uint2*)&sP[row*SPP + c0] = z;
    }
    const float* bias_h = biasf + h*9604;
    const float* mask_w = mask + w*9604;

    f32x4 oacc0 = fzero, oacc1 = fzero;
#pragma unroll 1
    for (int it = 0; it < 4; ++it) {
      const int mt = sub + it*2;
      const bool valid = mt < 7;
      if (valid) {
        f32x4 qa0 = fzero, qa1 = fzero;
#pragma unroll
        for (int ks = 0; ks < 4; ++ks) {
          const bf16x8 a = *(const bf16x8*)&sX[(mt*16 + l16)*SXP + ks*32 + quad*8];
          qa0 = __builtin_amdgcn_mfma_f32_16x16x32_bf16(a, qb[0][ks], qa0, 0, 0, 0);
          qa1 = __builtin_amdgcn_mfma_f32_16x16x32_bf16(a, qb[1][ks], qa1, 0, 0, 0);
        }
#pragma unroll
        for (int r = 0; r < 4; ++r) {
          sQ[(quad*4 + r)*SQP + l16]      = (bf16)((qa0[r] + qbias0) * SCALE_Q);
          sQ[(quad*4 + r)*SQP + 16 + l16] = (bf16)((qa1[r] + qbias1) * SCALE_Q);
        }
        const bf16x8 aq = *(const bf16x8*)&sQ[l16*SQP + quad*8];
        f32x4 s[7];
#pragma unroll
        for (int nt = 0; nt < 7; ++nt) {
          const bf16x8 bk2 = *(const bf16x8*)&sK[(h*NP + nt*16 + l16)*SKP + quad*8];
          s[nt] = __builtin_amdgcn_mfma_f32_16x16x32_bf16(aq, bk2, fzero, 0, 0, 0);
        }
#pragma unroll
        for (int r = 0; r < 4; ++r) {
          const int row = mt*16 + quad*4 + r;
          const bool rowok = row < NTOK;
          float mx = -3.0e38f;
#pragma unroll
          for (int nt = 0; nt < 7; ++nt) {
            const int col = nt*16 + l16;
            float sv;
            if (rowok && col < NTOK)
              sv = s[nt][r] + bias_h[row*NTOK + col] + mask_w[row*NTOK + col];
            else
              sv = -1.0e30f;
            s[nt][r] = sv;
            mx = fmaxf(mx, sv);
          }
#pragma unroll
          for (int off = 1; off < 16; off <<= 1)
            mx = fmaxf(mx, __shfl_xor(mx, off, 64));
          float sum = 0.f;
#pragma unroll
          for (int nt = 0; nt < 7; ++nt) {
            const float p = __expf(s[nt][r] - mx);
            s[nt][r] = p;
            sum += p;
          }
#pragma unroll
          for (int off = 1; off < 16; off <<= 1)
            sum += __shfl_xor(sum, off, 64);
          const float inv = __builtin_amdgcn_rcpf(sum);
#pragma unroll
          for (int nt = 0; nt < 7; ++nt)
            sP[(quad*4 + r)*SPP + nt*16 + l16] = (bf16)(s[nt][r] * inv);
        }
        oacc0 = fzero; oacc1 = fzero;
#pragma unroll
        for (int ks = 0; ks < 4; ++ks) {
          const bf16x8 ap = *(const bf16x8*)&sP[l16*SPP + ks*32 + quad*8];
          const bf16x8 bv0 = *(const bf16x8*)&sVT[(h*HD + l16)*SVP + ks*32 + quad*8];
          const bf16x8 bv1 = *(const bf16x8*)&sVT[(h*HD + 16 + l16)*SVP + ks*32 + quad*8];
          oacc0 = __builtin_amdgcn_mfma_f32_16x16x32_bf16(ap, bv0, oacc0, 0, 0, 0);
          oacc1 = __builtin_amdgcn_mfma_f32_16x16x32_bf16(ap, bv1, oacc1, 0, 0, 0);
        }
      }
      __syncthreads();
      if (valid) {
#pragma unroll
        for (int r = 0; r < 4; ++r) {
          sX[(mt*16 + quad*4 + r)*SXP + h*HD + l16]      = (bf16)(oacc0[r]);
          sX[(mt*16 + quad*4 + r)*SXP + h*HD + 16 + l16] = (bf16)(oacc1[r]);
        }
      }
    }
  }
  __syncthreads();

  {
    const int nt = wave;
    bf16x8 pbf[4];
#pragma unroll
    for (int ks = 0; ks < 4; ++ks)
      pbf[ks] = *(const bf16x8*)(PT + (nt*16 + l16)*DIM + ks*32 + quad*8);
    const float pb = proj_b[nt*16 + l16];
    float* outb = out + (size_t)b * (NTOK*DIM);
#pragma unroll
    for (int mt = 0; mt < 7; ++mt) {
      f32x4 acc = fzero;
#pragma unroll
      for (int ks = 0; ks < 4; ++ks) {
        const bf16x8 a = *(const bf16x8*)&sX[(mt*16 + l16)*SXP + ks*32 + quad*8];
        acc = __builtin_amdgcn_mfma_f32_16x16x32_bf16(a, pbf[ks], acc, 0, 0, 0);
      }
#pragma unroll
      for (int r = 0; r < 4; ++r) {
        const int row = mt*16 + quad*4 + r;
        if (row < NTOK)
          outb[row*DIM + nt*16 + l16] = acc[r] + pb;
      }
    }
  }
}

extern "C" void kernel_launch(void* const* d_in, const int* in_sizes, int n_in,
                              void* d_out, int out_size, void* d_ws, size_t ws_size,
                              hipStream_t stream)
{
  const float* x      = (const float*)d_in[0];
  const float* mask   = (const float*)d_in[1];
  const float* qkv_w  = (const float*)d_in[2];
  const float* qkv_b  = (const float*)d_in[3];
  const float* table  = (const float*)d_in[4];
  const int*   rel    = (const int*)d_in[5];
  const float* proj_w = (const float*)d_in[6];
  const float* proj_b = (const float*)d_in[7];
  float* out = (float*)d_out;
  char* ws = (char*)d_ws;

  if (ws_size >= WS_NEED) {
    bf16*  WTq   = (bf16*)(ws + WS_WTQ);
    bf16*  PT2   = (bf16*)(ws + WS_PT);
    float* bmt   = (float*)(ws + WS_BM);
    float* biasT = (float*)(ws + WS_BIAS);

    const int prepa_total = PREPA_SCALAR + PREPA_BIAS;   // 78080
    prep_a_kernel<<<(prepa_total + 255)/256, 256, 0, stream>>>(
        qkv_w, proj_w, table, rel, WTq, PT2, biasT);
    prep_b_kernel<<<(PREPB_TOTAL + 255)/256, 256, 0, stream>>>(mask, biasT, bmt);
    fused_kernel<<<2048, 256, 0, stream>>>(x, qkv_b, proj_b, WTq, PT2, bmt, out);
  } else {
    bf16*  WTq   = (bf16*)(ws + WS_WTQ);
    bf16*  PT    = (bf16*)(ws + WS_PT);
    float* biasf = (float*)(ws + WS_BM);
    const int prep_total = 384*128 + 128*128 + 98*98;
    prep_kernel<<<(prep_total + 255)/256, 256, 0, stream>>>(qkv_w, proj_w, table, rel, WTq, PT, biasf);
    win_attn_kernel<<<2048, 512, 0, stream>>>(x, mask, qkv_b, proj_b, WTq, PT, biasf, out);
  }
}